// Round 14
// baseline (125.376 us; speedup 1.0000x reference)
//
#include <hip/hip_runtime.h>
#include <math.h>

#define HH 256
#define WW 256
#define BB 8
#define MM 256
#define NN (HH * WW)
// one row per block -> 2048 blocks = 8 blocks/CU = 8 waves/SIMD

#define EPSI 1e-6f
#define MAXD 362.03867196751236f
#define EPS_OVER_MAXD (1e-6f / 362.03867196751236f)

static __device__ __forceinline__ float asqrt(float x) {
    return __builtin_amdgcn_sqrtf(x);     // single v_sqrt_f32
}
static __device__ __forceinline__ float min3(float a, float b, float c) {
    return fminf(fminf(a, b), c);         // folds to v_min3_f32
}

// ws layout (u32 units):
//   [0..15]                  sums (float s0,s1 per batch)
//   [16 .. 16+2048)          gmin, INVERTED float bits (0 == +inf)
//   [2064 .. +B*NN)          sc2 table: (1/(p^4+EPS/MAXD))^2 per (b,n) (2 MB)
//   [.. +2*B*MM)             gts: prescaled (gy*nfY, gx*nfX) per (b,m) (16 KB)
//   [.. +B*MM)               gxs: gx*nfX per (b,m)                     (8 KB)
#define WS_GMIN 16
#define WS_SC   2064
#define WS_GTS  (WS_SC + BB * NN)
#define WS_GXS  (WS_GTS + 2 * BB * MM)

// ---------------------------------------------------------------------------
// prep: sc^2 table + small hot GT tables. ~2 MB writes, memory-bound.
// ---------------------------------------------------------------------------
__global__ __launch_bounds__(256) void whd_prep(
    const float* __restrict__ pm, const float* __restrict__ gt,
    const float* __restrict__ osz, float* __restrict__ sc2,
    float2* __restrict__ gts, float* __restrict__ gxs)
{
    const int idx = blockIdx.x * 256 + threadIdx.x;   // 0 .. B*NN-1
    const float p  = pm[idx];
    const float p2 = p * p;
    const float s  = 1.0f / fmaf(p2, p2, EPS_OVER_MAXD);
    sc2[idx] = s * s;                     // squared: Phase B ranks by d^2*sc^2

    if (idx < BB * MM) {
        const int b = idx >> 8;
        const float nfY = osz[b * 2 + 0] * (1.0f / HH);
        const float nfX = osz[b * 2 + 1] * (1.0f / WW);
        const float2 g = ((const float2*)gt)[idx];
        gts[idx] = make_float2(g.x * nfY, g.y * nfX);
        gxs[idx] = g.y * nfX;
    }
}

// ---------------------------------------------------------------------------
// main: 1 row/block, 2048 blocks = 8/CU = 8 waves/SIMD. Phase A: LDS ey
// float4 broadcast + scalar gx4. Phase B: sqrt-free t=d2*sc2 with scalar sc2
// float4 stream, distance-2 prefetch. min3 chains. Fire-and-forget merges.
// ---------------------------------------------------------------------------
__global__ __launch_bounds__(256, 8) void whd_main(
    const float* __restrict__ pm, const float* __restrict__ osz,
    const float* __restrict__ sc2, const float2* __restrict__ gts,
    const float* __restrict__ gxs,
    float* __restrict__ sums, unsigned* __restrict__ gmin)
{
    __shared__ __align__(16) float sey[MM];    // ey per m (this row), 1 KB
    __shared__ float swred[8];

    const int tid = threadIdx.x;
    const int row = blockIdx.x;   // 0..255
    const int b   = blockIdx.y;

    const float nfY = osz[b * 2 + 0] * (1.0f / HH);
    const float nfX = osz[b * 2 + 1] * (1.0f / WW);
    const float y   = (float)row * nfY;
    const float x   = (float)tid * nfX;

    // own pixel (coalesced)
    const float p = pm[b * NN + row * WW + tid];

    // staging: thread tid owns GT m=tid -> ey into LDS + regs
    const float2 gm  = gts[b * MM + tid];     // per-lane, once
    const float  gxm = gm.y;
    const float  dy  = y - gm.x;
    const float  ey  = dy * dy;
    sey[tid] = ey;
    __syncthreads();

    // ---- Phase A: pixel col=tid; min_m (dx^2 + ey[m]). 4 m per iter:
    // 1 ds_read_b128 (broadcast) + 1 scalar float4 gx; 10 VALU / 4 pairs.
    const float4* sey4 = (const float4*)sey;            // 64 entries
    const float4* gx4p = (const float4*)(gxs + b * MM); // 64 entries, hot
    float4 e  = sey4[0], en  = sey4[1];
    float4 gx = gx4p[0], gxn = gx4p[1];
    float a0 = INFINITY, a1 = INFINITY;
    #pragma unroll 4
    for (int k = 0; k < MM / 4; ++k) {
        const int k2 = (k + 2) & 63;
        const float4 e2  = sey4[k2];          // distance-2 prefetch
        const float4 gx2 = gx4p[k2];
        const float dx0 = x - gx.x;
        const float dx1 = x - gx.y;
        const float dx2 = x - gx.z;
        const float dx3 = x - gx.w;
        a0 = min3(a0, fmaf(dx0, dx0, e.x), fmaf(dx1, dx1, e.y));
        a1 = min3(a1, fmaf(dx2, dx2, e.z), fmaf(dx3, dx3, e.w));
        e = en; en = e2; gx = gxn; gxn = gx2;
    }
    const float mind2 = fminf(a0, a1);

    // ---- Phase B: thread owns m=tid; rank by t = d2*sc2 (sqrt-free,
    // monotone). 4 cols/iter, scalar float4 sc2 with distance-2 prefetch;
    // 14 VALU / 4 pairs.
    const float4* sp = (const float4*)(sc2 + b * NN + row * WW);  // 64 entries
    float4 s = sp[0], sn = sp[1];
    float dx0 = 0.0f - gxm;
    float dx1 = dx0 + nfX;
    float dx2 = dx0 + 2.0f * nfX;
    float dx3 = dx0 + 3.0f * nfX;
    const float step = 4.0f * nfX;
    float c0 = INFINITY, c1 = INFINITY;
    #pragma unroll 4
    for (int k = 0; k < WW / 4; ++k) {
        const float4 s2 = sp[(k + 2) & 63];   // distance-2 prefetch
        const float q0 = fmaf(dx0, dx0, ey);
        const float q1 = fmaf(dx1, dx1, ey);
        const float q2 = fmaf(dx2, dx2, ey);
        const float q3 = fmaf(dx3, dx3, ey);
        c0 = min3(c0, q0 * s.x, q1 * s.y);
        c1 = min3(c1, q2 * s.z, q3 * s.w);
        dx0 += step; dx1 += step; dx2 += step; dx3 += step;
        s = sn; sn = s2;
    }
    const float cmin = asqrt(fminf(c0, c1));  // back to value space

    // ---- term1 partials (thread-exclusive pixel), one wave reduce
    float sum0 = p;
    float sum1 = p * asqrt(mind2);
    #pragma unroll
    for (int off = 32; off; off >>= 1) {
        sum0 += __shfl_down(sum0, off, 64);
        sum1 += __shfl_down(sum1, off, 64);
    }
    if ((tid & 63) == 0) { swred[(tid >> 6) * 2] = sum0; swred[(tid >> 6) * 2 + 1] = sum1; }
    __syncthreads();

    // fire-and-forget merges — no fence, no counter, no waiting
    if (tid == 0) {
        const float s0r = (swred[0] + swred[2]) + (swred[4] + swred[6]);
        const float s1r = (swred[1] + swred[3]) + (swred[5] + swred[7]);
        atomicAdd(&sums[b * 2 + 0], s0r);
        atomicAdd(&sums[b * 2 + 1], s1r);
    }
    atomicMax(&gmin[b * MM + tid], ~__float_as_uint(cmin));
}

// ---------------------------------------------------------------------------
__global__ __launch_bounds__(256) void whd_final(const float* __restrict__ sums,
                                                 const unsigned* __restrict__ gmin,
                                                 float* __restrict__ out) {
    __shared__ float gred[4];
    const int tid = threadIdx.x;

    float gacc = 0.0f;
    #pragma unroll
    for (int q = 0; q < BB; ++q) {
        const float v = __uint_as_float(~gmin[q * MM + tid]);
        gacc += fminf(fmaxf(v, 0.0f), MAXD);
    }
    #pragma unroll
    for (int off = 32; off; off >>= 1) gacc += __shfl_down(gacc, off, 64);
    if ((tid & 63) == 0) gred[tid >> 6] = gacc;
    __syncthreads();
    if (tid == 0) {
        float t1 = 0.0f;
        #pragma unroll
        for (int q = 0; q < BB; ++q)
            t1 += sums[q * 2 + 1] / (sums[q * 2 + 0] + EPSI);
        const float g2 = (gred[0] + gred[1]) + (gred[2] + gred[3]);
        out[0] = t1 * (1.0f / BB) + g2 * (1.0f / (BB * MM));
    }
}

// ---------------------------------------------------------------------------
extern "C" void kernel_launch(void* const* d_in, const int* in_sizes, int n_in,
                              void* d_out, int out_size, void* d_ws, size_t ws_size,
                              hipStream_t stream) {
    const float* pm  = (const float*)d_in[0];   // [B, H, W]
    const float* gt  = (const float*)d_in[1];   // [B, M, 2]
    const float* osz = (const float*)d_in[2];   // [B, 2]
    float* out = (float*)d_out;

    unsigned* ws0  = (unsigned*)d_ws;
    float*    sums = (float*)ws0;
    unsigned* gmin = ws0 + WS_GMIN;
    float*    sc2  = (float*)(ws0 + WS_SC);
    float2*   gts  = (float2*)(ws0 + WS_GTS);
    float*    gxs  = (float*)(ws0 + WS_GXS);

    // zero-init sums + gmin only (0 == +inf in inverted representation)
    hipMemsetAsync(ws0, 0, (WS_GMIN + BB * MM) * sizeof(unsigned), stream);

    whd_prep<<<BB * NN / 256, 256, 0, stream>>>(pm, gt, osz, sc2, gts, gxs);

    dim3 grid(HH, BB);
    whd_main<<<grid, 256, 0, stream>>>(pm, osz, sc2, gts, gxs, sums, gmin);

    whd_final<<<1, 256, 0, stream>>>(sums, gmin, out);
}

// Round 15
// 122.356 us; speedup vs baseline: 1.0247x; 1.0247x over previous
//
#include <hip/hip_runtime.h>
#include <math.h>

#define HH 256
#define WW 256
#define BB 8
#define MM 256
#define NN (HH * WW)
#define ROWS 2
#define BLKS_PER_B (HH / ROWS)            // 128 -> grid 1024 = 4 blocks/CU

#define EPSI 1e-6f
#define MAXD 362.03867196751236f
#define EPS_OVER_MAXD (1e-6f / 362.03867196751236f)

static __device__ __forceinline__ float asqrt(float x) {
    return __builtin_amdgcn_sqrtf(x);     // single v_sqrt_f32
}
static __device__ __forceinline__ float min3(float a, float b, float c) {
    return fminf(fminf(a, b), c);         // folds to v_min3_f32
}

// ws layout (u32 units):
//   [0..15]                     sums (float s0,s1 per batch)
//   [16 .. +B*BLKS*MM)          pmin: per-block per-m partial min (1 MB)
//   [.. +2*B*MM)                gts: prescaled (gy*nfY, gx*nfX) per (b,m) (16 KB, hot)
#define WS_PMIN 16
#define WS_GTS  (WS_PMIN + BB * BLKS_PER_B * MM)

// ---------------------------------------------------------------------------
// prep: tiny — GT table only (16 KB).
// ---------------------------------------------------------------------------
__global__ __launch_bounds__(256) void whd_prep(
    const float* __restrict__ gt, const float* __restrict__ osz,
    float2* __restrict__ gts)
{
    const int idx = blockIdx.x * 256 + threadIdx.x;   // 0 .. B*MM-1
    const int b = idx >> 8;
    const float nfY = osz[b * 2 + 0] * (1.0f / HH);
    const float nfX = osz[b * 2 + 1] * (1.0f / WW);
    const float2 g = ((const float2*)gt)[idx];
    gts[idx] = make_float2(g.x * nfY, g.y * nfX);
}

// ---------------------------------------------------------------------------
// main: 2 rows/block, 1024 blocks = 4/CU. Phase A: gts via s_load (hot),
// ey on the fly. Phase B: block-local sc2 in LDS (built from pm in staging).
// NO global tables except hot gts; NO contended atomics (plain pmin stores).
// ---------------------------------------------------------------------------
__global__ __launch_bounds__(256, 4) void whd_main(
    const float* __restrict__ pm, const float* __restrict__ osz,
    const float2* __restrict__ gts,
    float* __restrict__ sums, float* __restrict__ pmin)
{
    __shared__ __align__(16) float ssc0[WW];   // sc2 row0 per col, 1 KB
    __shared__ __align__(16) float ssc1[WW];   // sc2 row1 per col, 1 KB
    __shared__ float swred[8];

    const int tid = threadIdx.x;
    const int blk = blockIdx.x;   // 0..127
    const int b   = blockIdx.y;

    const float nfY = osz[b * 2 + 0] * (1.0f / HH);
    const float nfX = osz[b * 2 + 1] * (1.0f / WW);
    const int   r0  = blk * ROWS;
    const float y0  = (float)r0 * nfY;
    const float y1  = y0 + nfY;
    const float x   = (float)tid * nfX;

    // staging: own pixels -> sc2 into LDS; own GT point m=tid -> regs
    const float p0 = pm[b * NN + r0 * WW + tid];
    const float p1 = pm[b * NN + (r0 + 1) * WW + tid];
    const float q0s = p0 * p0, q1s = p1 * p1;
    const float v0 = 1.0f / fmaf(q0s, q0s, EPS_OVER_MAXD);
    const float v1 = 1.0f / fmaf(q1s, q1s, EPS_OVER_MAXD);
    ssc0[tid] = v0 * v0;                  // sc^2: Phase B ranks by d2*sc2
    ssc1[tid] = v1 * v1;

    const float2 gm  = gts[b * MM + tid];
    const float  gxm = gm.y;
    const float  dy0m = y0 - gm.x, dy1m = y1 - gm.x;
    const float  ey0m = dy0m * dy0m, ey1m = dy1m * dy1m;
    __syncthreads();

    // ---- Phase A: pixel col=tid (rows r0,r1); min_m d^2. 2 m/iter from the
    // HOT gts table via uniform s_load_dwordx4; ey on the fly (dx^2 shared
    // across the 2 m-row combos); distance-2 prefetch.
    const float4* gt4 = (const float4*)(gts + b * MM);   // 128 entries
    float4 g = gt4[0], gn = gt4[1];
    float a0 = INFINITY, a1 = INFINITY;
    #pragma unroll 4
    for (int k = 0; k < MM / 2; ++k) {
        const float4 g2 = gt4[(k + 2) & 127];   // prefetch
        const float dx0 = x - g.y;
        const float dx1 = x - g.w;
        const float xx0 = dx0 * dx0;
        const float xx1 = dx1 * dx1;
        const float dy00 = y0 - g.x, dy01 = y0 - g.z;
        const float dy10 = y1 - g.x, dy11 = y1 - g.z;
        a0 = min3(a0, fmaf(dy00, dy00, xx0), fmaf(dy01, dy01, xx1));
        a1 = min3(a1, fmaf(dy10, dy10, xx0), fmaf(dy11, dy11, xx1));
        g = gn; gn = g2;
    }
    // a0/a1 = min_m d^2 for (row0, row1) own pixel

    // ---- Phase B: thread owns m=tid; rank by t = d2*sc2 (sqrt-free,
    // monotone). 8 px/iter (4 cols x 2 rows, dx shared across rows) from
    // block-local LDS float4 broadcast; distance-2 prefetch.
    const float4* s0p = (const float4*)ssc0;   // 64 entries
    const float4* s1p = (const float4*)ssc1;
    float4 s0 = s0p[0], s0n = s0p[1];
    float4 s1 = s1p[0], s1n = s1p[1];
    float dx0 = 0.0f - gxm;
    float dx1 = dx0 + nfX;
    float dx2 = dx0 + 2.0f * nfX;
    float dx3 = dx0 + 3.0f * nfX;
    const float step = 4.0f * nfX;
    float c0 = INFINITY, c1 = INFINITY, c2 = INFINITY, c3 = INFINITY;
    #pragma unroll 4
    for (int k = 0; k < WW / 4; ++k) {
        const int k2 = (k + 2) & 63;
        const float4 s0f = s0p[k2];            // prefetch
        const float4 s1f = s1p[k2];
        const float t0 = fmaf(dx0, dx0, ey0m);
        const float t1 = fmaf(dx1, dx1, ey0m);
        const float t2 = fmaf(dx2, dx2, ey0m);
        const float t3 = fmaf(dx3, dx3, ey0m);
        const float u0 = fmaf(dx0, dx0, ey1m);
        const float u1 = fmaf(dx1, dx1, ey1m);
        const float u2 = fmaf(dx2, dx2, ey1m);
        const float u3 = fmaf(dx3, dx3, ey1m);
        c0 = min3(c0, t0 * s0.x, t1 * s0.y);
        c1 = min3(c1, t2 * s0.z, t3 * s0.w);
        c2 = min3(c2, u0 * s1.x, u1 * s1.y);
        c3 = min3(c3, u2 * s1.z, u3 * s1.w);
        dx0 += step; dx1 += step; dx2 += step; dx3 += step;
        s0 = s0n; s0n = s0f; s1 = s1n; s1n = s1f;
    }
    const float cmin = asqrt(fminf(fminf(c0, c1), fminf(c2, c3)));

    // contention-free partial-min store (no atomics)
    pmin[(b * BLKS_PER_B + blk) * MM + tid] = cmin;

    // ---- term1 partials (thread-exclusive pixels), one wave reduce
    float sum0 = p0 + p1;
    float sum1 = fmaf(p0, asqrt(a0), p1 * asqrt(a1));
    #pragma unroll
    for (int off = 32; off; off >>= 1) {
        sum0 += __shfl_down(sum0, off, 64);
        sum1 += __shfl_down(sum1, off, 64);
    }
    if ((tid & 63) == 0) { swred[(tid >> 6) * 2] = sum0; swred[(tid >> 6) * 2 + 1] = sum1; }
    __syncthreads();

    if (tid == 0) {
        const float s0r = (swred[0] + swred[2]) + (swred[4] + swred[6]);
        const float s1r = (swred[1] + swred[3]) + (swred[5] + swred[7]);
        atomicAdd(&sums[b * 2 + 0], s0r);     // fire-and-forget, 16 addrs only
        atomicAdd(&sums[b * 2 + 1], s1r);
    }
}

// ---------------------------------------------------------------------------
// final: 8 blocks (one per batch). Reduce pmin over the 128 blocks per (b,m),
// clip, mean; add term1 ratio; accumulate into out[0] (memset to 0 first).
// ---------------------------------------------------------------------------
__global__ __launch_bounds__(256) void whd_final(const float* __restrict__ sums,
                                                 const float* __restrict__ pmin,
                                                 float* __restrict__ out) {
    __shared__ float gred[4];
    const int tid = threadIdx.x;
    const int b   = blockIdx.x;

    const float* pb = pmin + b * BLKS_PER_B * MM + tid;
    float v = INFINITY;
    #pragma unroll 8
    for (int blk = 0; blk < BLKS_PER_B; ++blk)
        v = fminf(v, pb[blk * MM]);            // coalesced across tid
    float acc = fminf(fmaxf(v, 0.0f), MAXD);

    #pragma unroll
    for (int off = 32; off; off >>= 1) acc += __shfl_down(acc, off, 64);
    if ((tid & 63) == 0) gred[tid >> 6] = acc;
    __syncthreads();
    if (tid == 0) {
        const float t2b = (gred[0] + gred[1]) + (gred[2] + gred[3]);
        const float t1b = sums[b * 2 + 1] / (sums[b * 2 + 0] + EPSI);
        atomicAdd(out, t1b * (1.0f / BB) + t2b * (1.0f / (BB * MM)));
    }
}

// ---------------------------------------------------------------------------
extern "C" void kernel_launch(void* const* d_in, const int* in_sizes, int n_in,
                              void* d_out, int out_size, void* d_ws, size_t ws_size,
                              hipStream_t stream) {
    const float* pm  = (const float*)d_in[0];   // [B, H, W]
    const float* gt  = (const float*)d_in[1];   // [B, M, 2]
    const float* osz = (const float*)d_in[2];   // [B, 2]
    float* out = (float*)d_out;

    unsigned* ws0  = (unsigned*)d_ws;
    float*    sums = (float*)ws0;
    float*    pmin = (float*)(ws0 + WS_PMIN);
    float2*   gts  = (float2*)(ws0 + WS_GTS);

    hipMemsetAsync(sums, 0, 16 * sizeof(float), stream);   // sums = 0
    hipMemsetAsync(out, 0, sizeof(float), stream);         // out accumulator

    whd_prep<<<BB * MM / 256, 256, 0, stream>>>(gt, osz, gts);

    dim3 grid(BLKS_PER_B, BB);
    whd_main<<<grid, 256, 0, stream>>>(pm, osz, gts, sums, pmin);

    whd_final<<<BB, 256, 0, stream>>>(sums, pmin, out);
}